// Round 5
// baseline (141.225 us; speedup 1.0000x reference)
//
#include <hip/hip_runtime.h>

#define J 17
#define F 128
#define TB 16          // batches per block (= MFMA N dim)
#define THREADS 512    // 8 waves; wave w owns g band [16w, 16w+16)

typedef __attribute__((ext_vector_type(4))) float f32x4;
typedef __attribute__((ext_vector_type(8))) short bf16x8;   // 8 bf16 in 4 VGPRs

// round-to-nearest-even f32 -> bf16 (prep / M / epilogue)
__device__ __forceinline__ unsigned short f2bf(float f) {
    unsigned u = __builtin_bit_cast(unsigned, f);
    u += 0x7fffu + ((u >> 16) & 1u);
    return (unsigned short)(u >> 16);
}
__device__ __forceinline__ float bf2f(unsigned short s) {
    return __builtin_bit_cast(float, (unsigned)s << 16);
}

// pack two f32 (as raw bits) -> two bf16 with round-half-up: 2 v_add + 1 v_perm
__device__ __forceinline__ unsigned pkbf(unsigned lo, unsigned hi) {
    return __builtin_amdgcn_perm(hi + 0x8000u, lo + 0x8000u, 0x07060302u);
}

__device__ __forceinline__ f32x4 fma4(float a, f32x4 v, f32x4 c) {
    f32x4 av = {a, a, a, a};
    return __builtin_elementwise_fma(av, v, c);
}

// async global->LDS DMA, 16B per lane; LDS dest must be wave-uniform base
__device__ __forceinline__ void dma16(const void* g, void* l) {
    __builtin_amdgcn_global_load_lds(
        (const __attribute__((address_space(1))) unsigned*)g,
        (__attribute__((address_space(3))) unsigned*)l, 16, 0, 0);
}

// ws: f32[0..288] = A_off (diag zeroed); f32[289..305] = A_diag;
// byte 2048: WT bf16 [2][g=128][k=128]  (WT[mat][g][k] = bf16(W[mat][k][g]))
__global__ void prep(const float* __restrict__ W, const float* __restrict__ adj,
                     const float* __restrict__ adj2, float* __restrict__ wsA,
                     unsigned short* __restrict__ WT) {
    int t = blockIdx.x * 256 + threadIdx.x;
    for (int idx = t; idx < 2 * F * F; idx += 16 * 256) {
        int mat = idx >> 14;
        int rem = idx & 16383;
        int g = rem >> 7, k = rem & 127;
        WT[idx] = f2bf(W[mat * 16384 + k * F + g]);
    }
    if (blockIdx.x == 0) {
        for (int idx = threadIdx.x; idx < J * J; idx += 256) {
            int i = idx / J, j = idx % J;
            float a = 0.5f * (adj[i*J+j] + adj2[i*J+j] + adj[j*J+i] + adj2[j*J+i]);
            wsA[idx] = (i == j) ? 0.0f : a;
            if (i == j) wsA[J * J + i] = a;
        }
    }
}

// DMA one j-chunk (JC in {4,1}) of x (f32) into buf.
// LDS layout: lin = b*(JC*512) + jj*512 + kb, with kb pre-unswizzled at the
// SOURCE so that reads may apply  byte ^ ((b&7)<<4)  (both-sides rule, m173).
template<int JC>
__device__ __forceinline__ void stage_dma(const float* __restrict__ x,
        unsigned char* buf, int b0, int j0, int wave, int lane) {
#pragma unroll
    for (int c = 0; c < (TB * JC * 512) / (THREADS * 16); ++c) {
        unsigned lin = (unsigned)((c * 8 + wave) * 1024 + lane * 16);
        int b        = (int)(lin >> (JC == 4 ? 11 : 9));
        unsigned rem = lin & (unsigned)(JC * 512 - 1);
        int jj       = (int)(rem >> 9);
        unsigned kb  = (rem & 511u) ^ ((unsigned)(b & 7) << 4);
        const unsigned char* src = (const unsigned char*)x
            + (size_t)(b0 + b) * (J * F * 4) + (size_t)(j0 + jj) * 512 + kb;
        dma16(src, buf + (size_t)(c * 8 + wave) * 1024);   // uniform base
    }
}

// read 8 consecutive f32 of x from LDS, convert to bf16x8 fragment
template<int JC>
__device__ __forceinline__ bf16x8 read_frag(const unsigned char* buf,
                                            int b, int jj, int kf) {
    unsigned lin = (unsigned)(b * (JC * 512) + jj * 512 + kf * 4);
    unsigned swz = (unsigned)((b & 7) << 4);
    uint4 q0 = *(const uint4*)(buf + (lin ^ swz));
    uint4 q1 = *(const uint4*)(buf + ((lin + 16) ^ swz));
    uint4 r;
    r.x = pkbf(q0.x, q0.y); r.y = pkbf(q0.z, q0.w);
    r.z = pkbf(q1.x, q1.y); r.w = pkbf(q1.z, q1.w);
    return __builtin_bit_cast(bf16x8, r);
}

// merged h0/h1 pass over one j-chunk (acc is linear in j => exact split)
template<int JC, int J0>
__device__ __forceinline__ void compute_chunk(const unsigned char* buf,
        const unsigned short* MsB, const float* __restrict__ Aoff,
        const float* __restrict__ Adiag, const bf16x8* wf0, const bf16x8* wf1,
        f32x4* acc, int lrow, int lq, int gq) {
#pragma unroll
    for (int jj = 0; jj < JC; ++jj) {
        f32x4 h0 = {0.f, 0.f, 0.f, 0.f};
        f32x4 h1 = {0.f, 0.f, 0.f, 0.f};
#pragma unroll
        for (int ks = 0; ks < 4; ++ks) {
            bf16x8 xf = read_frag<JC>(buf, lrow, jj, ks * 32 + lq * 8);
            h0 = __builtin_amdgcn_mfma_f32_16x16x32_bf16(wf0[ks], xf, h0, 0, 0, 0);
            h1 = __builtin_amdgcn_mfma_f32_16x16x32_bf16(wf1[ks], xf, h1, 0, 0, 0);
        }
        const int j = J0 + jj;
        ushort4 m4 = *(const ushort4*)(MsB + j * F + gq);
        f32x4 mj = {bf2f(m4.x), bf2f(m4.y), bf2f(m4.z), bf2f(m4.w)};
        acc[j] = fma4(Adiag[j], mj * h0, acc[j]);
        f32x4 mh1 = mj * h1;
#pragma unroll
        for (int i = 0; i < J; ++i)
            acc[i] = fma4(Aoff[i * J + j], mh1, acc[i]);
    }
}

__global__ __launch_bounds__(THREADS, 2) void mgcn_kernel(
    const float* __restrict__ x, const float* __restrict__ Mw,
    const float* __restrict__ bias, const float* __restrict__ wsA,
    const unsigned short* __restrict__ WT, float* __restrict__ out) {

    __shared__ __align__(16) unsigned char xs[65536];      // 2 x 32KB dbuf; epilogue reuse
    __shared__ __align__(16) unsigned short MsB[J * F];    // 4352 B -> total 69888 B

    const int tid  = threadIdx.x;
    const int b0   = blockIdx.x * TB;
    const int wave = tid >> 6;
    const int lane = tid & 63;
    const int lrow = lane & 15;           // MFMA 16-index: D col = batch
    const int lq   = lane >> 4;
    const int grow = wave * 16 + lrow;    // A-frag (W^T) row = g
    const int gq   = wave * 16 + lq * 4;  // D reg-quad g base

    // M -> LDS as bf16
    for (int idx = tid; idx < J * F / 4; idx += THREADS) {
        float4 v = ((const float4*)Mw)[idx];
        ushort4 u;
        u.x = f2bf(v.x); u.y = f2bf(v.y); u.z = f2bf(v.z); u.w = f2bf(v.w);
        *(ushort4*)(MsB + idx * 4) = u;
    }

    // persistent W^T fragments (32 VGPRs) — loaded BEFORE first barrier so the
    // chunk loop issues no pure global loads (DMA prefetch never drained early)
    bf16x8 wf0[4], wf1[4];
#pragma unroll
    for (int ks = 0; ks < 4; ++ks) {
        const unsigned short* p0 = WT + (size_t)grow * F + ks * 32 + lq * 8;
        wf0[ks] = __builtin_bit_cast(bf16x8, *(const uint4*)p0);
        wf1[ks] = __builtin_bit_cast(bf16x8, *(const uint4*)(p0 + F * F));
    }

    const f32x4 bias4 = *(const f32x4*)(bias + gq);
    f32x4 acc[J];
#pragma unroll
    for (int i = 0; i < J; ++i) acc[i] = bias4;

    const float* __restrict__ Aoff  = wsA;
    const float* __restrict__ Adiag = wsA + J * J;
    unsigned char* buf0 = xs;
    unsigned char* buf1 = xs + 32768;

    stage_dma<4>(x, buf0, b0, 0, wave, lane);
    __syncthreads();                                        // drains DMA + wf + Ms

    stage_dma<4>(x, buf1, b0, 4, wave, lane);               // prefetch j 4..7
    compute_chunk<4, 0>(buf0, MsB, Aoff, Adiag, wf0, wf1, acc, lrow, lq, gq);
    __syncthreads();
    stage_dma<4>(x, buf0, b0, 8, wave, lane);               // prefetch j 8..11
    compute_chunk<4, 4>(buf1, MsB, Aoff, Adiag, wf0, wf1, acc, lrow, lq, gq);
    __syncthreads();
    stage_dma<4>(x, buf1, b0, 12, wave, lane);              // prefetch j 12..15
    compute_chunk<4, 8>(buf0, MsB, Aoff, Adiag, wf0, wf1, acc, lrow, lq, gq);
    __syncthreads();
    stage_dma<1>(x, buf0, b0, 16, wave, lane);              // prefetch j 16
    compute_chunk<4, 12>(buf1, MsB, Aoff, Adiag, wf0, wf1, acc, lrow, lq, gq);
    __syncthreads();
    compute_chunk<1, 16>(buf0, MsB, Aoff, Adiag, wf0, wf1, acc, lrow, lq, gq);
    __syncthreads();                                        // xs free for epilogue

    // ---- epilogue: acc -> bf16 LDS tile (8 batches/round) -> coalesced stores ----
#pragma unroll 1
    for (int r = 0; r < 2; ++r) {
        if (r) __syncthreads();
        if ((lrow >> 3) == r) {
            const int bl = lrow & 7;
            const unsigned base = (unsigned)(bl * (J * 256) + gq * 2);
            const unsigned key  = (unsigned)((bl & 7) << 3);
#pragma unroll
            for (int i = 0; i < J; ++i) {
                ushort4 u;
                u.x = f2bf(acc[i][0]); u.y = f2bf(acc[i][1]);
                u.z = f2bf(acc[i][2]); u.w = f2bf(acc[i][3]);
                *(ushort4*)(xs + ((base + (unsigned)(i * 256)) ^ key)) = u;
            }
        }
        __syncthreads();
        const size_t gbase = ((size_t)b0 + r * 8) * (J * F);
        for (int idx = tid; idx < 8 * J * F / 4; idx += THREADS) {   // 4352
            unsigned byte = (unsigned)idx * 8u;
            unsigned bl   = byte / (unsigned)(J * 256);              // /4352
            ushort4 u = *(const ushort4*)(xs + (byte ^ ((bl & 7) << 3)));
            float4 o;
            o.x = bf2f(u.x); o.y = bf2f(u.y); o.z = bf2f(u.z); o.w = bf2f(u.w);
            *(float4*)(out + gbase + (size_t)idx * 4) = o;
        }
    }
}

extern "C" void kernel_launch(void* const* d_in, const int* in_sizes, int n_in,
                              void* d_out, int out_size, void* d_ws, size_t ws_size,
                              hipStream_t stream) {
    const float* x    = (const float*)d_in[0];
    const float* W    = (const float*)d_in[1];
    const float* Mw   = (const float*)d_in[2];
    const float* adj  = (const float*)d_in[3];
    const float* adj2 = (const float*)d_in[4];
    const float* bias = (const float*)d_in[5];
    float* out = (float*)d_out;
    float* wsA = (float*)d_ws;
    unsigned short* WT = (unsigned short*)((char*)d_ws + 2048);

    int Btot = in_sizes[0] / (J * F);   // 16384
    prep<<<16, 256, 0, stream>>>(W, adj, adj2, wsA, WT);
    mgcn_kernel<<<Btot / TB, THREADS, 0, stream>>>(x, Mw, bias, wsA, WT, out);
}

// Round 6
// 122.761 us; speedup vs baseline: 1.1504x; 1.1504x over previous
//
#include <hip/hip_runtime.h>

#define J 17
#define F 128
#define TB 16          // batches per block (= MFMA N dim)
#define THREADS 512    // 8 waves; wave w owns g band [16w, 16w+16)

typedef __attribute__((ext_vector_type(4))) float f32x4;
typedef __attribute__((ext_vector_type(8))) short bf16x8;   // 8 bf16 in 4 VGPRs

// round-to-nearest-even f32 -> bf16 (prep)
__device__ __forceinline__ unsigned short f2bf(float f) {
    unsigned u = __builtin_bit_cast(unsigned, f);
    u += 0x7fffu + ((u >> 16) & 1u);
    return (unsigned short)(u >> 16);
}
__device__ __forceinline__ float bf2f(unsigned short s) {
    return __builtin_bit_cast(float, (unsigned)s << 16);
}
// pack two f32 (raw bits) -> two bf16, round-half-up: 2 v_add + 1 v_perm
__device__ __forceinline__ unsigned pkbf(unsigned lo, unsigned hi) {
    return __builtin_amdgcn_perm(hi + 0x8000u, lo + 0x8000u, 0x07060302u);
}
__device__ __forceinline__ f32x4 fma4(float a, f32x4 v, f32x4 c) {
    f32x4 av = {a, a, a, a};
    return __builtin_elementwise_fma(av, v, c);
}

// ws: f32[0..288] = A_off (diag zeroed); f32[289..305] = A_diag;
// byte 2048: WT bf16 [2][g=128][k=128]  (WT[mat][g][k] = bf16(W[mat][k][g]))
__global__ void prep(const float* __restrict__ W, const float* __restrict__ adj,
                     const float* __restrict__ adj2, float* __restrict__ wsA,
                     unsigned short* __restrict__ WT) {
    int t = blockIdx.x * 256 + threadIdx.x;
    for (int idx = t; idx < 2 * F * F; idx += 16 * 256) {
        int mat = idx >> 14;
        int rem = idx & 16383;
        int g = rem >> 7, k = rem & 127;
        WT[idx] = f2bf(W[mat * 16384 + k * F + g]);
    }
    if (blockIdx.x == 0) {
        for (int idx = threadIdx.x; idx < J * J; idx += 256) {
            int i = idx / J, j = idx % J;
            float a = 0.5f * (adj[i*J+j] + adj2[i*J+j] + adj[j*J+i] + adj2[j*J+i]);
            wsA[idx] = (i == j) ? 0.0f : a;
            if (i == j) wsA[J * J + i] = a;
        }
    }
}

// ---- staging: JC*512 float4 per chunk, JC per thread -------------------
template<int JC>
__device__ __forceinline__ void stage_load(const float* __restrict__ x,
        int b0, int j0, int tid, float4* s) {
#pragma unroll
    for (int it = 0; it < JC; ++it) {
        int fi = it * THREADS + tid;
        int b  = fi / (JC * 32);
        int r  = fi - b * (JC * 32);
        int jj = r >> 5;
        int k4 = r & 31;
        s[it] = *(const float4*)(x + (size_t)(b0 + b) * (J * F)
                                   + (j0 + jj) * F + k4 * 4);
    }
}
template<int JC>
__device__ __forceinline__ void stage_write(unsigned char* buf, int tid,
                                            const float4* s) {
#pragma unroll
    for (int it = 0; it < JC; ++it) {
        int fi = it * THREADS + tid;
        int b  = fi / (JC * 32);
        int r  = fi - b * (JC * 32);
        int jj = r >> 5;
        int k4 = r & 31;
        unsigned byte = (unsigned)(b * (JC * 256) + jj * 256 + k4 * 8);
        byte ^= (unsigned)((b & 7) << 4);
        uint4 u = __builtin_bit_cast(uint4, s[it]);
        uint2 p;
        p.x = pkbf(u.x, u.y);
        p.y = pkbf(u.z, u.w);
        *(uint2*)(buf + byte) = p;
    }
}

// ---- merged h0/h1 compute over one j-chunk (acc linear in j) ------------
template<int JC, int J0>
__device__ __forceinline__ void compute_chunk(const unsigned char* buf,
        const unsigned short* MsB, const float* __restrict__ Aoff,
        const float* __restrict__ Adiag, const bf16x8* wf0, const bf16x8* wf1,
        f32x4* acc, int lrow, int lq, int gq) {
    const unsigned rbase = (unsigned)(lrow * (JC * 256));
    const unsigned swz   = (unsigned)((lrow & 7) << 4);
#pragma unroll
    for (int jj = 0; jj < JC; ++jj) {
        f32x4 h0 = {0.f, 0.f, 0.f, 0.f};
        f32x4 h1 = {0.f, 0.f, 0.f, 0.f};
#pragma unroll
        for (int ks = 0; ks < 4; ++ks) {
            unsigned byte = (rbase + (unsigned)(jj * 256 + ks * 64 + lq * 16)) ^ swz;
            bf16x8 xf = __builtin_bit_cast(bf16x8, *(const uint4*)(buf + byte));
            h0 = __builtin_amdgcn_mfma_f32_16x16x32_bf16(wf0[ks], xf, h0, 0, 0, 0);
            h1 = __builtin_amdgcn_mfma_f32_16x16x32_bf16(wf1[ks], xf, h1, 0, 0, 0);
        }
        const int j = J0 + jj;
        ushort4 m4 = *(const ushort4*)(MsB + j * F + gq);
        f32x4 mj = {bf2f(m4.x), bf2f(m4.y), bf2f(m4.z), bf2f(m4.w)};
        acc[j] = fma4(Adiag[j], mj * h0, acc[j]);
        f32x4 mh1 = mj * h1;
#pragma unroll
        for (int i = 0; i < J; ++i)
            acc[i] = fma4(Aoff[i * J + j], mh1, acc[i]);
    }
}

__global__ __launch_bounds__(THREADS, 2) void mgcn_kernel(
    const float* __restrict__ x, const float* __restrict__ Mw,
    const float* __restrict__ bias, const float* __restrict__ wsA,
    const unsigned short* __restrict__ WT, float* __restrict__ out) {

    __shared__ __align__(16) unsigned char xs0[TB * 4 * F * 2];   // 16384 B
    __shared__ __align__(16) unsigned char xs1[TB * 4 * F * 2];   // 16384 B
    __shared__ __align__(16) unsigned short MsB[J * F];           //  4352 B

    const int tid  = threadIdx.x;
    const int b0   = blockIdx.x * TB;
    const int wave = tid >> 6;
    const int lane = tid & 63;
    const int lrow = lane & 15;           // MFMA 16-index: D col = batch
    const int lq   = lane >> 4;
    const int grow = wave * 16 + lrow;    // A-frag (W^T) row = g
    const int gq   = wave * 16 + lq * 4;  // D reg-quad g base

    // M -> LDS as bf16
    for (int idx = tid; idx < J * F / 4; idx += THREADS) {
        float4 v = ((const float4*)Mw)[idx];
        uint4 u = __builtin_bit_cast(uint4, v);
        uint2 p; p.x = pkbf(u.x, u.y); p.y = pkbf(u.z, u.w);
        *(uint2*)(MsB + idx * 4) = p;
    }

    // persistent W^T fragments (32 VGPRs), loaded before the first barrier
    bf16x8 wf0[4], wf1[4];
#pragma unroll
    for (int ks = 0; ks < 4; ++ks) {
        const unsigned short* p0 = WT + (size_t)grow * F + ks * 32 + lq * 8;
        wf0[ks] = __builtin_bit_cast(bf16x8, *(const uint4*)p0);
        wf1[ks] = __builtin_bit_cast(bf16x8, *(const uint4*)(p0 + F * F));
    }

    const f32x4 bias4 = *(const f32x4*)(bias + gq);
    f32x4 acc[J];
#pragma unroll
    for (int i = 0; i < J; ++i) acc[i] = bias4;

    const float* __restrict__ Aoff  = wsA;
    const float* __restrict__ Adiag = wsA + J * J;

    float4 s[4];
    // prologue: stage j 0..3
    stage_load<4>(x, b0, 0, tid, s);
    stage_write<4>(xs0, tid, s);
    __syncthreads();

    // chunk 0 (j 0..3) | prefetch j 4..7
    stage_load<4>(x, b0, 4, tid, s);
    compute_chunk<4, 0>(xs0, MsB, Aoff, Adiag, wf0, wf1, acc, lrow, lq, gq);
    stage_write<4>(xs1, tid, s);
    __syncthreads();
    // chunk 1 (j 4..7) | prefetch j 8..11
    stage_load<4>(x, b0, 8, tid, s);
    compute_chunk<4, 4>(xs1, MsB, Aoff, Adiag, wf0, wf1, acc, lrow, lq, gq);
    stage_write<4>(xs0, tid, s);
    __syncthreads();
    // chunk 2 (j 8..11) | prefetch j 12..15
    stage_load<4>(x, b0, 12, tid, s);
    compute_chunk<4, 8>(xs0, MsB, Aoff, Adiag, wf0, wf1, acc, lrow, lq, gq);
    stage_write<4>(xs1, tid, s);
    __syncthreads();
    // chunk 3 (j 12..15) | prefetch tail j 16 (1 float4/thread)
    stage_load<1>(x, b0, 16, tid, s);
    compute_chunk<4, 12>(xs1, MsB, Aoff, Adiag, wf0, wf1, acc, lrow, lq, gq);
    stage_write<1>(xs0, tid, s);
    __syncthreads();
    // tail chunk (j 16)
    compute_chunk<1, 16>(xs0, MsB, Aoff, Adiag, wf0, wf1, acc, lrow, lq, gq);

    // ---- epilogue: direct f32x4 stores (lane owns out[b0+lrow, i, gq..gq+3]) ----
    float* ob = out + ((size_t)(b0 + lrow) * J) * F + gq;
#pragma unroll
    for (int i = 0; i < J; ++i)
        *(f32x4*)(ob + (size_t)i * F) = acc[i];
}

extern "C" void kernel_launch(void* const* d_in, const int* in_sizes, int n_in,
                              void* d_out, int out_size, void* d_ws, size_t ws_size,
                              hipStream_t stream) {
    const float* x    = (const float*)d_in[0];
    const float* W    = (const float*)d_in[1];
    const float* Mw   = (const float*)d_in[2];
    const float* adj  = (const float*)d_in[3];
    const float* adj2 = (const float*)d_in[4];
    const float* bias = (const float*)d_in[5];
    float* out = (float*)d_out;
    float* wsA = (float*)d_ws;
    unsigned short* WT = (unsigned short*)((char*)d_ws + 2048);

    int Btot = in_sizes[0] / (J * F);   // 16384
    prep<<<16, 256, 0, stream>>>(W, adj, adj2, wsA, WT);
    mgcn_kernel<<<Btot / TB, THREADS, 0, stream>>>(x, Mw, bias, wsA, WT, out);
}